// Round 18
// baseline (1002.849 us; speedup 1.0000x reference)
//
#include <hip/hip_runtime.h>
#include <hip/hip_fp16.h>
#include <hip/hip_cooperative_groups.h>

namespace cg = cooperative_groups;

#define NN 100000     // num nodes
#define NE 1600000    // num edges
#define NEL 200000    // link-pred edges

// Bucketed CSR build (R12 config): bucket = dst >> 9 (512 dsts per bucket).
#define NBUCK 196     // ceil(NN/512)
#define CAPB  10240   // per-bucket capacity (mean 8163, sigma ~90)
#define TPE   8192    // edges per part tile (196 tiles)
#define NT1   1563    // ceil(NN/64)  hw1 tiles
#define NT2   1563    // ceil(NN/64)  hw2 tiles (TM2=64)
#define NU_G  25000   // gather units (4 rows each)
#define NU_LP 12500   // linkpred units (16 edges each)

// Union'd LDS: max member 31 KB -> 5 blocks/CU co-resident (160 KB budget),
// ~20 waves/CU for the latency-bound gather phases (~= R16 occupancy).
// hw1.sh stride 81 (was 80): 80 gave node-group stride 320 words = 0 mod 32
// -> 16-way bank conflict on every h-read; 81 -> stride 324 = 4 mod 32 ->
// 2-way, which is free [m136].
union SharedU {
    struct { int hist[NBUCK], base[NBUCK], rk[NBUCK]; } part;
    struct { int cnts[256]; int hist[512]; int loff[512]; int ssum[256]; } build;
    struct { float sh[64 * 81]; __half sw[80 * 64]; } hw1;   // 20736+10240 B
    struct { float sh[64 * 65]; float sw[64 * 32]; } hw2;    // 16640+8192 B
};

__global__ __launch_bounds__(256, 4) void k_mega(
        const int* __restrict__ src, const int* __restrict__ dst,
        const float* __restrict__ x, const float* __restrict__ pos,
        const float* __restrict__ W1, const float* __restrict__ b1,
        const float* __restrict__ W2, const float* __restrict__ b2,
        const float* __restrict__ Wl, const float* __restrict__ bl,
        const int* __restrict__ lsrc, const int* __restrict__ ldst,
        int* __restrict__ gcur, int* __restrict__ part,
        int* __restrict__ csr, int* __restrict__ off,
        float* __restrict__ dinv, __half* __restrict__ hw1,
        __half* __restrict__ h2buf, __half* __restrict__ hw2,
        float* __restrict__ outz, float* __restrict__ pred)
{
    cg::grid_group grid = cg::this_grid();
    __shared__ SharedU S;
    int tid  = threadIdx.x;
    int bid  = blockIdx.x;
    int nblk = gridDim.x;
    int lane = tid & 63;
    int wave = tid >> 6;

    // ---------------- phase 0: zero bucket counters ----------------
    if (bid == 0)
        for (int i = tid; i < NBUCK; i += 256) gcur[i] = 0;
    grid.sync();

    // ---------------- phase 1: partition edges into buckets --------
    for (int tile = bid; tile < NBUCK; tile += nblk) {
        for (int i = tid; i < NBUCK; i += 256) { S.part.hist[i] = 0; S.part.rk[i] = 0; }
        __syncthreads();
        int e0 = tile * TPE;
        int e1 = min(e0 + TPE, NE);
        for (int e = e0 + tid; e < e1; e += 256)
            atomicAdd(&S.part.hist[dst[e] >> 9], 1);
        __syncthreads();
        for (int i = tid; i < NBUCK; i += 256)
            S.part.base[i] = i * CAPB + atomicAdd(&gcur[i], S.part.hist[i]);
        __syncthreads();
        for (int e = e0 + tid; e < e1; e += 256) {
            int d = dst[e];
            int s = src[e];
            int b = d >> 9;
            int r = atomicAdd(&S.part.rk[b], 1);
            part[S.part.base[b] + r] = ((d & 511) << 17) | s;   // src < 2^17
        }
        __syncthreads();
    }
    grid.sync();

    // ---------------- phase 2: per-bucket sort -> csr/off/dinv ------
    // Direct global scatter replaces the 40 KB LDS csrbuf: each bucket's
    // 32 KB csr window is written by one block only -> L2-resident, lines
    // accumulate before writeback.
    for (int b = bid; b < NBUCK; b += nblk) {
        S.build.cnts[tid] = (tid < NBUCK) ? gcur[tid] : 0;   // inline prefix
        __syncthreads();
        for (int st = 1; st < 256; st <<= 1) {
            int tmp = (tid >= st) ? S.build.cnts[tid - st] : 0;
            __syncthreads();
            S.build.cnts[tid] += tmp;
            __syncthreads();
        }
        int obase = (b == 0) ? 0 : S.build.cnts[b - 1];
        int cnt = gcur[b];
        int pbase = b * CAPB;
        S.build.hist[tid] = 0; S.build.hist[tid + 256] = 0;
        __syncthreads();
        for (int i = tid; i < cnt; i += 256)
            atomicAdd(&S.build.hist[part[pbase + i] >> 17], 1);
        __syncthreads();
        int a0 = S.build.hist[2 * tid], a1 = S.build.hist[2 * tid + 1];
        int pairs = a0 + a1;
        S.build.ssum[tid] = pairs;
        __syncthreads();
        for (int st = 1; st < 256; st <<= 1) {
            int tmp = (tid >= st) ? S.build.ssum[tid - st] : 0;
            __syncthreads();
            S.build.ssum[tid] += tmp;
            __syncthreads();
        }
        int pexcl = S.build.ssum[tid] - pairs;
        S.build.loff[2 * tid] = pexcl;
        S.build.loff[2 * tid + 1] = pexcl + a0;
        __syncthreads();
        for (int i = tid; i < 512; i += 256) {
            int d = b * 512 + i;
            if (d < NN) {
                int c = S.build.hist[i];
                off[d] = obase + S.build.loff[i] + c;        // end of row d
                dinv[d] = rsqrtf((float)(c + 1));            // +1 self-loop
            }
        }
        S.build.hist[tid] = 0; S.build.hist[tid + 256] = 0;  // rank counters
        __syncthreads();
        for (int i = tid; i < cnt; i += 256) {
            int rec = part[pbase + i];
            int dl = rec >> 17;
            int r = atomicAdd(&S.build.hist[dl], 1);
            csr[obase + S.build.loff[dl] + r] = rec & 0x1FFFF;
        }
        __syncthreads();
    }
    grid.sync();

    // ---------------- phase 3: hw1' = dinv * ([x|pos] @ W1) ---------
    for (int t = tid; t < 80 * 64; t += 256)
        S.hw1.sw[t] = __float2half(W1[t]);                   // W1 fp16 in LDS
    for (int tile = bid; tile < NT1; tile += nblk) {
        __syncthreads();        // sw ready / previous tile's readers done
        int nb = tile * 64;
        for (int i = tid; i < 64 * 64; i += 256) {
            int node = i >> 6, ch = i & 63;
            int g = nb + node;
            S.hw1.sh[node * 81 + ch] = (g < NN) ? x[g * 64 + ch] : 0.0f;
        }
        for (int i = tid; i < 64 * 16; i += 256) {
            int node = i >> 4, ch = i & 15;
            int g = nb + node;
            S.hw1.sh[node * 81 + 64 + ch] = (g < NN) ? pos[g * 16 + ch] : 0.0f;
        }
        __syncthreads();
        int j  = (tid & 15) * 4;
        int nl = (tid >> 4) * 4;
        float a00=0,a01=0,a02=0,a03=0, a10=0,a11=0,a12=0,a13=0;
        float a20=0,a21=0,a22=0,a23=0, a30=0,a31=0,a32=0,a33=0;
#pragma unroll 4
        for (int k = 0; k < 80; ++k) {
            float2 wr = *(const float2*)&S.hw1.sw[k * 64 + j];   // 4 halves
            __half2 wA = *(__half2*)&wr.x;
            __half2 wB = *(__half2*)&wr.y;
            float2 wAf = __half22float2(wA);
            float2 wBf = __half22float2(wB);
            float h0 = S.hw1.sh[(nl + 0) * 81 + k];
            float h1 = S.hw1.sh[(nl + 1) * 81 + k];
            float h2 = S.hw1.sh[(nl + 2) * 81 + k];
            float h3 = S.hw1.sh[(nl + 3) * 81 + k];
            a00 += h0 * wAf.x; a01 += h0 * wAf.y; a02 += h0 * wBf.x; a03 += h0 * wBf.y;
            a10 += h1 * wAf.x; a11 += h1 * wAf.y; a12 += h1 * wBf.x; a13 += h1 * wBf.y;
            a20 += h2 * wAf.x; a21 += h2 * wAf.y; a22 += h2 * wBf.x; a23 += h2 * wBf.y;
            a30 += h3 * wAf.x; a31 += h3 * wAf.y; a32 += h3 * wBf.x; a33 += h3 * wBf.y;
        }
        int g0 = nb + nl;
        union { __half2 hv[2]; float2 f2; } u;
#define STORE_ROW(r, b0, b1, b2, b3)                                          \
        if (g0 + r < NN) {                                                    \
            float sc = dinv[g0 + r];                                          \
            u.hv[0] = __floats2half2_rn(b0 * sc, b1 * sc);                    \
            u.hv[1] = __floats2half2_rn(b2 * sc, b3 * sc);                    \
            *(float2*)&hw1[(g0 + r) * 64 + j] = u.f2;                         \
        }
        STORE_ROW(0, a00, a01, a02, a03)
        STORE_ROW(1, a10, a11, a12, a13)
        STORE_ROW(2, a20, a21, a22, a23)
        STORE_ROW(3, a30, a31, a32, a33)
#undef STORE_ROW
    }
    grid.sync();

    // ---------------- phase 4: layer-1 gather (R16 core) ------------
    for (int u = bid; u < NU_G; u += nblk) {
        int d = u * 4 + wave;
        int start = (d == 0) ? 0 : off[d - 1];
        int end = off[d];
        start = __builtin_amdgcn_readfirstlane(start);
        end   = __builtin_amdgcn_readfirstlane(end);
        float dd = dinv[d];
        float hself = __half2float(hw1[d * 64 + lane]);
        float acc0 = 0.0f, acc1 = 0.0f, acc2 = 0.0f, acc3 = 0.0f;
        int e = start;
        for (; e + 7 < end; e += 8) {          // 8 outstanding gathers
            int s0 = csr[e],     s1 = csr[e + 1];
            int s2 = csr[e + 2], s3 = csr[e + 3];
            int s4 = csr[e + 4], s5 = csr[e + 5];
            int s6 = csr[e + 6], s7 = csr[e + 7];
            float g0 = __half2float(hw1[s0 * 64 + lane]);
            float g1 = __half2float(hw1[s1 * 64 + lane]);
            float g2 = __half2float(hw1[s2 * 64 + lane]);
            float g3 = __half2float(hw1[s3 * 64 + lane]);
            float g4 = __half2float(hw1[s4 * 64 + lane]);
            float g5 = __half2float(hw1[s5 * 64 + lane]);
            float g6 = __half2float(hw1[s6 * 64 + lane]);
            float g7 = __half2float(hw1[s7 * 64 + lane]);
            acc0 += g0; acc1 += g1; acc2 += g2; acc3 += g3;
            acc0 += g4; acc1 += g5; acc2 += g6; acc3 += g7;
        }
        for (; e < end; ++e)
            acc0 += __half2float(hw1[csr[e] * 64 + lane]);
        float v = fmaxf(b1[lane] + dd * (((acc0 + acc1) + (acc2 + acc3)) + hself), 0.0f);
        h2buf[d * 64 + lane] = __float2half_rn(v);
    }
    grid.sync();

    // ---------------- phase 5: hw2' = dinv * (h2 @ W2), TM2=64 ------
    for (int t = tid; t < 64 * 32; t += 256)
        S.hw2.sw[t] = W2[t];
    for (int tile = bid; tile < NT2; tile += nblk) {
        __syncthreads();
        int nb = tile * 64;
        for (int i = tid; i < 64 * 64; i += 256) {
            int node = i >> 6, ch = i & 63;
            int g = nb + node;
            S.hw2.sh[node * 65 + ch] = (g < NN) ? __half2float(h2buf[g * 64 + ch]) : 0.0f;
        }
        __syncthreads();
        int j  = (tid & 7) * 4;
        int nl = (tid >> 3) * 2;                // 32 groups x 2 nodes
        float a00=0,a01=0,a02=0,a03=0, a10=0,a11=0,a12=0,a13=0;
#pragma unroll 4
        for (int k = 0; k < 64; ++k) {
            float4 wv = *(const float4*)&S.hw2.sw[k * 32 + j];
            float h0 = S.hw2.sh[(nl + 0) * 65 + k];
            float h1 = S.hw2.sh[(nl + 1) * 65 + k];
            a00 += h0 * wv.x; a01 += h0 * wv.y; a02 += h0 * wv.z; a03 += h0 * wv.w;
            a10 += h1 * wv.x; a11 += h1 * wv.y; a12 += h1 * wv.z; a13 += h1 * wv.w;
        }
        int g0 = nb + nl;
        union { __half2 hv[2]; float2 f2; } u;
#define STORE_ROW2(r, b0, b1, b2, b3)                                         \
        if (g0 + r < NN) {                                                    \
            float sc = dinv[g0 + r];                                          \
            u.hv[0] = __floats2half2_rn(b0 * sc, b1 * sc);                    \
            u.hv[1] = __floats2half2_rn(b2 * sc, b3 * sc);                    \
            *(float2*)&hw2[(g0 + r) * 32 + j] = u.f2;                         \
        }
        STORE_ROW2(0, a00, a01, a02, a03)
        STORE_ROW2(1, a10, a11, a12, a13)
#undef STORE_ROW2
    }
    grid.sync();

    // ---------------- phase 6: layer-2 gather (R16 core) ------------
    for (int u = bid; u < NU_G; u += nblk) {
        int d = u * 4 + wave;
        int half = lane >> 5;
        int j = lane & 31;
        int start = (d == 0) ? 0 : off[d - 1];
        int end = off[d];
        start = __builtin_amdgcn_readfirstlane(start);
        end   = __builtin_amdgcn_readfirstlane(end);
        float dd = dinv[d];
        float hself = __half2float(hw2[d * 32 + j]);
        float accA = 0.0f, accB = 0.0f, accC = 0.0f, accD = 0.0f;
        int e = start;
        for (; e + 7 < end; e += 8) {
            int sA = csr[e + half];
            int sB = csr[e + half + 2];
            int sC = csr[e + half + 4];
            int sD = csr[e + half + 6];
            accA += __half2float(hw2[sA * 32 + j]);
            accB += __half2float(hw2[sB * 32 + j]);
            accC += __half2float(hw2[sC * 32 + j]);
            accD += __half2float(hw2[sD * 32 + j]);
        }
        for (int ee = e + half; ee < end; ee += 2)   // divergent-safe tail
            accA += __half2float(hw2[csr[ee] * 32 + j]);
        float acc = (accA + accB) + (accC + accD);
        acc += __shfl(acc, lane ^ 32, 64);           // full exec
        if (half == 0)
            outz[d * 32 + j] = b2[j] + dd * (acc + hself);
    }
    grid.sync();

    // ---------------- phase 7: link prediction (16 lanes/edge) ------
    for (int u = bid; u < NU_LP; u += nblk) {
        int g = u * 256 + tid;
        int e = g >> 4;
        int l = g & 15;
        int s = lsrc[e], d = ldst[e];
        float2 zs = *(const float2*)&outz[s * 32 + 2 * l];
        float2 zd = *(const float2*)&outz[d * 32 + 2 * l];
        float2 ws = *(const float2*)&Wl[2 * l];
        float2 wd = *(const float2*)&Wl[32 + 2 * l];
        float v = zs.x * ws.x + zs.y * ws.y + zd.x * wd.x + zd.y * wd.y;
        v += __shfl_xor(v, 1, 64);
        v += __shfl_xor(v, 2, 64);
        v += __shfl_xor(v, 4, 64);
        v += __shfl_xor(v, 8, 64);
        if (l == 0) pred[e] = v + bl[0];
    }
}

extern "C" void kernel_launch(void* const* d_in, const int* in_sizes, int n_in,
                              void* d_out, int out_size, void* d_ws, size_t ws_size,
                              hipStream_t stream) {
    const float* x    = (const float*)d_in[0];
    const float* pos  = (const float*)d_in[1];
    const float* W1   = (const float*)d_in[2];
    const float* b1   = (const float*)d_in[3];
    const float* W2   = (const float*)d_in[4];
    const float* b2   = (const float*)d_in[5];
    const float* Wl   = (const float*)d_in[6];
    const float* bl   = (const float*)d_in[7];
    const int*   ei   = (const int*)d_in[8];   // [2, NE]
    const int*   eli  = (const int*)d_in[9];   // [2, NEL]
    const int* src  = ei;
    const int* dst  = ei + NE;
    const int* lsrc = eli;
    const int* ldst = eli + NEL;

    float* out_z    = (float*)d_out;            // [NN, 32]
    float* out_pred = (float*)d_out + NN * 32;  // [NEL]

    // workspace: dinv[NN]f | off[NN]i | gcur[NBUCK] | csr[NE]i |
    //            hw1'[NN*64]h (aliases part[NBUCK*CAPB]i, dead after phase 2)
    //            | h2[NN*64]h | hw2'[NN*32]h   ~= 39.2 MB
    float*  dinv  = (float*)d_ws;
    int*    off   = (int*)(dinv + NN);
    int*    gcur  = off + NN;
    int*    csr   = gcur + NBUCK;
    __half* hw1   = (__half*)(csr + NE);
    int*    part  = (int*)hw1;                  // 8.0 MB <= hw1's 12.8 MB
    __half* h2    = hw1 + NN * 64;
    __half* hw2   = h2 + NN * 64;

    // grid = co-resident capacity (cooperative launch requirement); pure
    // host-side occupancy query, deterministic, graph-capture safe.
    int occ = 0;
    hipOccupancyMaxActiveBlocksPerMultiprocessor(&occ, k_mega, 256, 0);
    if (occ < 1) occ = 1;
    int nblk = occ * 256;                       // 256 CUs

    void* args[] = { (void*)&src, (void*)&dst, (void*)&x, (void*)&pos,
                     (void*)&W1, (void*)&b1, (void*)&W2, (void*)&b2,
                     (void*)&Wl, (void*)&bl, (void*)&lsrc, (void*)&ldst,
                     (void*)&gcur, (void*)&part, (void*)&csr, (void*)&off,
                     (void*)&dinv, (void*)&hw1, (void*)&h2, (void*)&hw2,
                     (void*)&out_z, (void*)&out_pred };
    hipLaunchCooperativeKernel((const void*)k_mega, dim3(nblk), dim3(256),
                               args, 0, stream);
}